// Round 1
// baseline (310.236 us; speedup 1.0000x reference)
//
#include <hip/hip_runtime.h>
#include <math.h>

constexpr int B = 128, N = 512, HID = 512, NH = 8, DH = 64;

// ---------------------------------------------------------------------------
// K1: query = w_seed_w*seed + w_seed_b; q = w_q @ query;
//     qk[h][j] = (1/sqrt(DH)) * sum_d q[h*64+d] * w_v[(h*64+d)*HID + j]
// grid 64 (h = bid>>3, jc = bid&7), block 64
// ---------------------------------------------------------------------------
__global__ __launch_bounds__(64) void k1_qk(
    const float* __restrict__ w_q, const float* __restrict__ w_v,
    const float* __restrict__ w_sw, const float* __restrict__ w_sb,
    const float* __restrict__ seed, float* __restrict__ qk)
{
    __shared__ __align__(16) float query_s[HID];
    __shared__ float q_s[DH];
    const int t  = threadIdx.x;
    const int h  = blockIdx.x >> 3;
    const int jc = blockIdx.x & 7;
    const float sv = seed[0];
    #pragma unroll
    for (int k = 0; k < 8; ++k) {
        const int j = t * 8 + k;
        query_s[j] = w_sw[j] * sv + w_sb[j];
    }
    __syncthreads();
    {
        const float* row = w_q + (size_t)(h * DH + t) * HID;
        float acc = 0.f;
        for (int j = 0; j < HID; j += 4) {
            const float4 wv = *(const float4*)(row + j);
            acc += wv.x * query_s[j]     + wv.y * query_s[j + 1]
                 + wv.z * query_s[j + 2] + wv.w * query_s[j + 3];
        }
        q_s[t] = acc;
    }
    __syncthreads();
    {
        const int j = jc * 64 + t;
        float acc = 0.f;
        for (int d = 0; d < DH; ++d)
            acc += q_s[d] * w_v[(size_t)(h * DH + d) * HID + j];
        qk[h * HID + j] = acc * 0.125f;   // fold 1/sqrt(64)
    }
}

// ---------------------------------------------------------------------------
// K2: e[b][hh][n] = <h[b,n,:], qk[hh,:]>   (scale already folded into qk)
// grid B*4 (b = bid>>2, 128-row chunk c = bid&3), block 256.
// Thread pair (half = t&1) splits each row's j-range, interleaved by float4
// for 32B-contiguous coalescing; combine via shfl_xor(1).
// Rows n >= lengths[b] are skipped entirely (their e is never read).
// ---------------------------------------------------------------------------
__global__ __launch_bounds__(256) void k2_e(
    const float* __restrict__ hbuf, const int* __restrict__ lengths,
    const float* __restrict__ qk, float* __restrict__ e_ws)
{
    __shared__ __align__(16) float qk_s[NH * HID];
    const int t = threadIdx.x;
    const int b = blockIdx.x >> 2;
    const int c = blockIdx.x & 3;
    for (int i = t * 4; i < NH * HID; i += 256 * 4)
        *(float4*)&qk_s[i] = *(const float4*)&qk[i];
    __syncthreads();

    const int r    = t >> 1;       // row within chunk, 0..127
    const int half = t & 1;
    const int n    = c * 128 + r;
    const int len  = lengths[b];
    if (n >= len) return;

    const float* row = hbuf + (size_t)(b * N + n) * HID + half * 4;
    float acc[NH];
    #pragma unroll
    for (int hh = 0; hh < NH; ++hh) acc[hh] = 0.f;

    for (int q8 = 0; q8 < HID; q8 += 8) {
        const float4 hv = *(const float4*)(row + q8);
        const int j = q8 + half * 4;
        #pragma unroll
        for (int hh = 0; hh < NH; ++hh) {
            const float4 qv = *(const float4*)&qk_s[hh * HID + j];
            acc[hh] += hv.x * qv.x + hv.y * qv.y + hv.z * qv.z + hv.w * qv.w;
        }
    }
    #pragma unroll
    for (int hh = 0; hh < NH; ++hh)
        acc[hh] += __shfl_xor(acc[hh], 1, 64);
    if (half == 0) {
        #pragma unroll
        for (int hh = 0; hh < NH; ++hh)
            e_ws[(size_t)(b * NH + hh) * N + n] = acc[hh];
    }
}

// ---------------------------------------------------------------------------
// K2b: masked softmax over n per (b,hh); writes alpha (incl. zeros for n>=len)
// grid B, block 256 (4 waves; wave w handles heads w and w+4)
// ---------------------------------------------------------------------------
__global__ __launch_bounds__(256) void k2b_softmax(
    const float* __restrict__ e_ws, const int* __restrict__ lengths,
    float* __restrict__ alpha)
{
    const int b    = blockIdx.x;
    const int lane = threadIdx.x & 63;
    const int w    = threadIdx.x >> 6;
    const int len  = lengths[b];
    for (int hh = w; hh < NH; hh += 4) {
        const float* e = e_ws + (size_t)(b * NH + hh) * N;
        float ev[8];
        float m = -3.0e38f;
        #pragma unroll
        for (int it = 0; it < 8; ++it) {
            const int n = it * 64 + lane;
            ev[it] = (n < len) ? e[n] : -3.0e38f;
            m = fmaxf(m, ev[it]);
        }
        #pragma unroll
        for (int off = 32; off; off >>= 1)
            m = fmaxf(m, __shfl_xor(m, off, 64));
        float s = 0.f;
        #pragma unroll
        for (int it = 0; it < 8; ++it) {
            ev[it] = __expf(ev[it] - m);   // invalid slots -> exp(~-3e38) = 0
            s += ev[it];
        }
        #pragma unroll
        for (int off = 32; off; off >>= 1)
            s += __shfl_xor(s, off, 64);
        const float inv = 1.f / s;
        float* ao = alpha + (size_t)(b * NH + hh) * N;
        #pragma unroll
        for (int it = 0; it < 8; ++it) {
            const int n = it * 64 + lane;
            ao[n] = (n < len) ? ev[it] * inv : 0.f;
        }
    }
}

// ---------------------------------------------------------------------------
// K3: partial ctx[b,c][hh][j] = sum_{n in chunk c, n < len} alpha[b,hh,n]*h[b,n,j]
// grid B*4, block 256; thread owns j-pair (float2); whole row loaded coalesced
// per iteration; alpha broadcast from LDS as two float4s.
// ---------------------------------------------------------------------------
__global__ __launch_bounds__(256) void k3_ctx(
    const float* __restrict__ hbuf, const int* __restrict__ lengths,
    const float* __restrict__ alpha, float* __restrict__ ctxp)
{
    __shared__ __align__(16) float al_s[128][8];
    const int t  = threadIdx.x;
    const int b  = blockIdx.x >> 2;
    const int c  = blockIdx.x & 3;
    const int n0 = c * 128;
    const int len = lengths[b];
    for (int i = t; i < 128 * 8; i += 256) {
        const int hh = i >> 7, nl = i & 127;
        al_s[nl][hh] = alpha[(size_t)(b * NH + hh) * N + n0 + nl];
    }
    __syncthreads();

    const int nend = min(len - n0, 128);
    float2 acc[NH];
    #pragma unroll
    for (int hh = 0; hh < NH; ++hh) { acc[hh].x = 0.f; acc[hh].y = 0.f; }

    const float* hb = hbuf + (size_t)(b * N + n0) * HID + t * 2;
    for (int ln = 0; ln < nend; ++ln) {
        const float2 hv = *(const float2*)(hb + (size_t)ln * HID);
        const float4 a0 = *(const float4*)&al_s[ln][0];
        const float4 a1 = *(const float4*)&al_s[ln][4];
        acc[0].x += a0.x * hv.x; acc[0].y += a0.x * hv.y;
        acc[1].x += a0.y * hv.x; acc[1].y += a0.y * hv.y;
        acc[2].x += a0.z * hv.x; acc[2].y += a0.z * hv.y;
        acc[3].x += a0.w * hv.x; acc[3].y += a0.w * hv.y;
        acc[4].x += a1.x * hv.x; acc[4].y += a1.x * hv.y;
        acc[5].x += a1.y * hv.x; acc[5].y += a1.y * hv.y;
        acc[6].x += a1.z * hv.x; acc[6].y += a1.z * hv.y;
        acc[7].x += a1.w * hv.x; acc[7].y += a1.w * hv.y;
    }
    #pragma unroll
    for (int hh = 0; hh < NH; ++hh)
        *(float2*)&ctxp[(size_t)((b * 4 + c) * NH + hh) * HID + t * 2] = acc[hh];
}

// ---------------------------------------------------------------------------
// K4: ctx = sum of 4 partials; out_h[p] = <ctx[hh], w_v[p,:]> (p = hh*64+d);
//     out[b,i] = <out_h, w_o[i,:]>
// grid B, block 256
// ---------------------------------------------------------------------------
__global__ __launch_bounds__(256) void k4_out(
    const float* __restrict__ ctxp, const float* __restrict__ w_v,
    const float* __restrict__ w_o, float* __restrict__ out)
{
    __shared__ __align__(16) float ctx_s[NH * HID];
    __shared__ __align__(16) float oh_s[HID];
    const int t = threadIdx.x;
    const int b = blockIdx.x;
    const float* p0 = ctxp + (size_t)(b * 4) * NH * HID;
    for (int i = t; i < NH * HID; i += 256)
        ctx_s[i] = p0[i] + p0[NH * HID + i] + p0[2 * NH * HID + i] + p0[3 * NH * HID + i];
    __syncthreads();
    #pragma unroll
    for (int rep = 0; rep < 2; ++rep) {
        const int p  = rep * 256 + t;
        const int hh = p >> 6;
        const float* wrow = w_v + (size_t)p * HID;
        float acc = 0.f;
        for (int j = 0; j < HID; j += 4) {
            const float4 wv = *(const float4*)(wrow + j);
            const float4 cv = *(const float4*)&ctx_s[hh * HID + j];
            acc += wv.x * cv.x + wv.y * cv.y + wv.z * cv.z + wv.w * cv.w;
        }
        oh_s[p] = acc;
    }
    __syncthreads();
    #pragma unroll
    for (int rep = 0; rep < 2; ++rep) {
        const int i = rep * 256 + t;
        const float* wrow = w_o + (size_t)i * HID;
        float acc = 0.f;
        for (int j = 0; j < HID; j += 4) {
            const float4 wv = *(const float4*)(wrow + j);
            const float4 ov = *(const float4*)&oh_s[j];
            acc += wv.x * ov.x + wv.y * ov.y + wv.z * ov.z + wv.w * ov.w;
        }
        out[(size_t)b * HID + i] = acc;
    }
}

// ---------------------------------------------------------------------------
extern "C" void kernel_launch(void* const* d_in, const int* in_sizes, int n_in,
                              void* d_out, int out_size, void* d_ws, size_t ws_size,
                              hipStream_t stream) {
    const float* h     = (const float*)d_in[0];
    const int*   lens  = (const int*)  d_in[1];
    const float* w_q   = (const float*)d_in[2];
    // d_in[3] = w_k: dead compute in the reference, intentionally unused
    const float* w_v   = (const float*)d_in[4];
    const float* w_o   = (const float*)d_in[5];
    const float* w_sw  = (const float*)d_in[6];
    const float* w_sb  = (const float*)d_in[7];
    const float* seed  = (const float*)d_in[8];

    float* out   = (float*)d_out;            // [B, HID]
    float* alpha = out + (size_t)B * HID;    // [B, NH, N, 1]

    // ws layout (floats): qk[NH*HID] | e[B*NH*N] | ctxp[B*4*NH*HID]  (~10.5 MB)
    float* ws   = (float*)d_ws;
    float* qk   = ws;
    float* e_ws = qk + NH * HID;
    float* ctxp = e_ws + (size_t)B * NH * N;

    hipLaunchKernelGGL(k1_qk,       dim3(64),    dim3(64),  0, stream,
                       w_q, w_v, w_sw, w_sb, seed, qk);
    hipLaunchKernelGGL(k2_e,        dim3(B * 4), dim3(256), 0, stream,
                       h, lens, qk, e_ws);
    hipLaunchKernelGGL(k2b_softmax, dim3(B),     dim3(256), 0, stream,
                       e_ws, lens, alpha);
    hipLaunchKernelGGL(k3_ctx,      dim3(B * 4), dim3(256), 0, stream,
                       h, lens, alpha, ctxp);
    hipLaunchKernelGGL(k4_out,      dim3(B),     dim3(256), 0, stream,
                       ctxp, w_v, w_o, out);
}

// Round 2
// 305.739 us; speedup vs baseline: 1.0147x; 1.0147x over previous
//
#include <hip/hip_runtime.h>
#include <math.h>

constexpr int B = 128, N = 512, HID = 512, NH = 8, DH = 64;

// ---------------------------------------------------------------------------
// K1: query = w_seed_w*seed + w_seed_b; q = w_q @ query;
//     qk[h][j] = (1/sqrt(DH)) * sum_d q[h*64+d] * w_v[(h*64+d)*HID + j]
// grid 64 (h = bid>>3, jc = bid&7), block 64
// ---------------------------------------------------------------------------
__global__ __launch_bounds__(64) void k1_qk(
    const float* __restrict__ w_q, const float* __restrict__ w_v,
    const float* __restrict__ w_sw, const float* __restrict__ w_sb,
    const float* __restrict__ seed, float* __restrict__ qk)
{
    __shared__ __align__(16) float query_s[HID];
    __shared__ float q_s[DH];
    const int t  = threadIdx.x;
    const int h  = blockIdx.x >> 3;
    const int jc = blockIdx.x & 7;
    const float sv = seed[0];
    #pragma unroll
    for (int k = 0; k < 8; ++k) {
        const int j = t * 8 + k;
        query_s[j] = w_sw[j] * sv + w_sb[j];
    }
    __syncthreads();
    {
        const float* row = w_q + (size_t)(h * DH + t) * HID;
        float acc = 0.f;
        for (int j = 0; j < HID; j += 4) {
            const float4 wv = *(const float4*)(row + j);
            acc += wv.x * query_s[j]     + wv.y * query_s[j + 1]
                 + wv.z * query_s[j + 2] + wv.w * query_s[j + 3];
        }
        q_s[t] = acc;
    }
    __syncthreads();
    {
        const int j = jc * 64 + t;
        float acc = 0.f;
        for (int d = 0; d < DH; ++d)
            acc += q_s[d] * w_v[(size_t)(h * DH + d) * HID + j];
        qk[h * HID + j] = acc * 0.125f;   // fold 1/sqrt(64)
    }
}

// ---------------------------------------------------------------------------
// K2: e[b][hh][n] = <h[b,n,:], qk[hh,:]>
// grid B*4 (b=bid>>2, 128-row chunk c=bid&3), block 256 = 4 waves.
// Wave layout: group g = wave>>1 picks rows g*64..g*64+63 (lane = row),
// hb = wave&1 picks which 256-float half of the row this wave covers.
// qk addresses are WAVE-UNIFORM (lane-independent) -> scalar loads, no LDS
// in the hot loop. Halves combined via a small padded-LDS reduction.
// ---------------------------------------------------------------------------
__global__ __launch_bounds__(256) void k2_e(
    const float* __restrict__ hbuf, const int* __restrict__ lengths,
    const float* __restrict__ qk, float* __restrict__ e_ws)
{
    __shared__ float part[2][2][64][9];   // [group][half][row][head(+pad)]
    const int t    = threadIdx.x;
    const int lane = t & 63;
    const int wave = t >> 6;
    const int b    = blockIdx.x >> 2;
    const int c    = blockIdx.x & 3;
    const int g    = __builtin_amdgcn_readfirstlane(wave >> 1);
    const int hb   = __builtin_amdgcn_readfirstlane(wave & 1);
    const int n    = c * 128 + g * 64 + lane;
    const int len  = lengths[b];

    float acc[NH];
    #pragma unroll
    for (int hh = 0; hh < NH; ++hh) acc[hh] = 0.f;

    if (n < len) {
        const float* row = hbuf + (size_t)(b * N + n) * HID + hb * 256;
        const float* qkb = qk + hb * 256;            // uniform base
        #pragma unroll 4
        for (int q = 0; q < 256; q += 8) {
            const float4 h0 = *(const float4*)(row + q);
            const float4 h1 = *(const float4*)(row + q + 4);
            #pragma unroll
            for (int hh = 0; hh < NH; ++hh) {
                const float* qp = qkb + hh * HID + q;   // wave-uniform addr
                acc[hh] += h0.x * qp[0] + h0.y * qp[1] + h0.z * qp[2] + h0.w * qp[3]
                         + h1.x * qp[4] + h1.y * qp[5] + h1.z * qp[6] + h1.w * qp[7];
            }
        }
    }
    #pragma unroll
    for (int hh = 0; hh < NH; ++hh)
        part[g][hb][lane][hh] = acc[hh];             // lane stride 9 words: no conflicts
    __syncthreads();

    // combine halves: 1024 (g,row,head) sums over 256 threads
    #pragma unroll
    for (int v = t; v < 2 * 64 * NH; v += 256) {
        const int gg = v >> 9, r = (v >> 3) & 63, hh = v & 7;
        const int n2 = c * 128 + gg * 64 + r;
        if (n2 < len)
            e_ws[(size_t)(b * NH + hh) * N + n2] =
                part[gg][0][r][hh] + part[gg][1][r][hh];
    }
}

// ---------------------------------------------------------------------------
// K2b: masked softmax over n per (b,hh); writes alpha output (head-major,
// with zeros for n>=len) AND an interleaved copy al_t[b][n][hh] for K3's
// scalar-load path. grid B, block 256 (wave w handles heads w, w+4).
// ---------------------------------------------------------------------------
__global__ __launch_bounds__(256) void k2b_softmax(
    const float* __restrict__ e_ws, const int* __restrict__ lengths,
    float* __restrict__ alpha, float* __restrict__ al_t)
{
    const int b    = blockIdx.x;
    const int lane = threadIdx.x & 63;
    const int w    = threadIdx.x >> 6;
    const int len  = lengths[b];
    for (int hh = w; hh < NH; hh += 4) {
        const float* e = e_ws + (size_t)(b * NH + hh) * N;
        float ev[8];
        float m = -3.0e38f;
        #pragma unroll
        for (int it = 0; it < 8; ++it) {
            const int n = it * 64 + lane;
            ev[it] = (n < len) ? e[n] : -3.0e38f;
            m = fmaxf(m, ev[it]);
        }
        #pragma unroll
        for (int off = 32; off; off >>= 1)
            m = fmaxf(m, __shfl_xor(m, off, 64));
        float s = 0.f;
        #pragma unroll
        for (int it = 0; it < 8; ++it) {
            ev[it] = __expf(ev[it] - m);
            s += ev[it];
        }
        #pragma unroll
        for (int off = 32; off; off >>= 1)
            s += __shfl_xor(s, off, 64);
        const float inv = 1.f / s;
        float* ao = alpha + (size_t)(b * NH + hh) * N;
        float* at = al_t + (size_t)b * N * NH + hh;
        #pragma unroll
        for (int it = 0; it < 8; ++it) {
            const int n   = it * 64 + lane;
            const float v = (n < len) ? ev[it] * inv : 0.f;
            ao[n]         = v;
            at[n * NH]    = v;
        }
    }
}

// ---------------------------------------------------------------------------
// K3: partial ctx[b,c][hh][j] over 64-row chunk c.
// grid B*8, block 256; thread owns j-pair (float2): wave reads 512 B
// contiguous per row. Alpha comes from al_t at a BLOCK-UNIFORM global
// address -> scalar s_load_dwordx8, zero LDS in the hot loop.
// ---------------------------------------------------------------------------
__global__ __launch_bounds__(256) void k3_ctx(
    const float* __restrict__ hbuf, const int* __restrict__ lengths,
    const float* __restrict__ al_t, float* __restrict__ ctxp)
{
    const int t   = threadIdx.x;
    const int b   = blockIdx.x >> 3;
    const int c   = blockIdx.x & 7;
    const int n0  = c * 64;
    const int len = lengths[b];
    const int nend = min(len - n0, 64);

    float2 acc[NH];
    #pragma unroll
    for (int hh = 0; hh < NH; ++hh) { acc[hh].x = 0.f; acc[hh].y = 0.f; }

    const float* hb = hbuf + (size_t)(b * N + n0) * HID + t * 2;
    const float* ap = al_t + (size_t)(b * N + n0) * NH;   // uniform
    #pragma unroll 2
    for (int ln = 0; ln < nend; ++ln) {
        const float2 hv = *(const float2*)(hb + (size_t)ln * HID);
        const float* a = ap + ln * NH;                     // uniform addr
        acc[0].x += a[0] * hv.x; acc[0].y += a[0] * hv.y;
        acc[1].x += a[1] * hv.x; acc[1].y += a[1] * hv.y;
        acc[2].x += a[2] * hv.x; acc[2].y += a[2] * hv.y;
        acc[3].x += a[3] * hv.x; acc[3].y += a[3] * hv.y;
        acc[4].x += a[4] * hv.x; acc[4].y += a[4] * hv.y;
        acc[5].x += a[5] * hv.x; acc[5].y += a[5] * hv.y;
        acc[6].x += a[6] * hv.x; acc[6].y += a[6] * hv.y;
        acc[7].x += a[7] * hv.x; acc[7].y += a[7] * hv.y;
    }
    #pragma unroll
    for (int hh = 0; hh < NH; ++hh)
        *(float2*)&ctxp[(size_t)((b * 8 + c) * NH + hh) * HID + t * 2] = acc[hh];
}

// ---------------------------------------------------------------------------
// K4: ctx = sum of 8 partials; out_h[p] = <ctx[hh], w_v[p,:]> (p = hh*64+d);
//     out[b,i] = <out_h, w_o[i,:]>. grid B, block 256.
// ---------------------------------------------------------------------------
__global__ __launch_bounds__(256) void k4_out(
    const float* __restrict__ ctxp, const float* __restrict__ w_v,
    const float* __restrict__ w_o, float* __restrict__ out)
{
    __shared__ __align__(16) float ctx_s[NH * HID];
    __shared__ __align__(16) float oh_s[HID];
    const int t = threadIdx.x;
    const int b = blockIdx.x;
    const float* p0 = ctxp + (size_t)(b * 8) * NH * HID;
    for (int i = t; i < NH * HID; i += 256) {
        float s = 0.f;
        #pragma unroll
        for (int cc = 0; cc < 8; ++cc) s += p0[cc * NH * HID + i];
        ctx_s[i] = s;
    }
    __syncthreads();
    #pragma unroll
    for (int rep = 0; rep < 2; ++rep) {
        const int p  = rep * 256 + t;
        const int hh = p >> 6;
        const float* wrow = w_v + (size_t)p * HID;
        float acc = 0.f;
        for (int j = 0; j < HID; j += 4) {
            const float4 wv = *(const float4*)(wrow + j);
            const float4 cv = *(const float4*)&ctx_s[hh * HID + j];
            acc += wv.x * cv.x + wv.y * cv.y + wv.z * cv.z + wv.w * cv.w;
        }
        oh_s[p] = acc;
    }
    __syncthreads();
    #pragma unroll
    for (int rep = 0; rep < 2; ++rep) {
        const int i = rep * 256 + t;
        const float* wrow = w_o + (size_t)i * HID;
        float acc = 0.f;
        for (int j = 0; j < HID; j += 4) {
            const float4 wv = *(const float4*)(wrow + j);
            const float4 ov = *(const float4*)&oh_s[j];
            acc += wv.x * ov.x + wv.y * ov.y + wv.z * ov.z + wv.w * ov.w;
        }
        out[(size_t)b * HID + i] = acc;
    }
}

// ---------------------------------------------------------------------------
extern "C" void kernel_launch(void* const* d_in, const int* in_sizes, int n_in,
                              void* d_out, int out_size, void* d_ws, size_t ws_size,
                              hipStream_t stream) {
    const float* h     = (const float*)d_in[0];
    const int*   lens  = (const int*)  d_in[1];
    const float* w_q   = (const float*)d_in[2];
    // d_in[3] = w_k: dead compute in the reference, intentionally unused
    const float* w_v   = (const float*)d_in[4];
    const float* w_o   = (const float*)d_in[5];
    const float* w_sw  = (const float*)d_in[6];
    const float* w_sb  = (const float*)d_in[7];
    const float* seed  = (const float*)d_in[8];

    float* out   = (float*)d_out;            // [B, HID]
    float* alpha = out + (size_t)B * HID;    // [B, NH, N, 1]

    // ws layout (floats): qk[NH*HID] | e[B*NH*N] | al_t[B*N*NH] | ctxp[B*8*NH*HID]
    float* ws   = (float*)d_ws;
    float* qk   = ws;
    float* e_ws = qk + NH * HID;
    float* al_t = e_ws + (size_t)B * NH * N;
    float* ctxp = al_t + (size_t)B * N * NH;

    hipLaunchKernelGGL(k1_qk,       dim3(64),    dim3(64),  0, stream,
                       w_q, w_v, w_sw, w_sb, seed, qk);
    hipLaunchKernelGGL(k2_e,        dim3(B * 4), dim3(256), 0, stream,
                       h, lens, qk, e_ws);
    hipLaunchKernelGGL(k2b_softmax, dim3(B),     dim3(256), 0, stream,
                       e_ws, lens, alpha, al_t);
    hipLaunchKernelGGL(k3_ctx,      dim3(B * 8), dim3(256), 0, stream,
                       h, lens, al_t, ctxp);
    hipLaunchKernelGGL(k4_out,      dim3(B),     dim3(256), 0, stream,
                       ctxp, w_v, w_o, out);
}